// Round 5
// baseline (239.391 us; speedup 1.0000x reference)
//
#include <hip/hip_runtime.h>
#include <cmath>

#define HH 1024
#define WW 1024
#define KS 51
#define RAD 25
#define PLANE (HH * WW)

struct GaussW { float w[KS]; };

// ---------------------------------------------------------------------------
// Horizontal 51-tap blur, wave-per-row, LDS-staged.
// R4 change: phase 2 now PRELOADS all 18 window float4s from LDS into
// registers before the FMA block (LDS latency 120cy decoupled from the FMA
// chain; 18 in-order ds_read_b128 pipeline at ~12cy each). Rest unchanged
// (R2: proven -47%, SQ_LDS_BANK_CONFLICT == 0).
// ---------------------------------------------------------------------------
__global__ __launch_bounds__(256) void hblur_kernel(const float* __restrict__ x,
                                                    float* __restrict__ tmp,
                                                    GaussW gw)
{
    __shared__ __align__(16) float lds[4][1024];   // 16 KB / block

    const int t    = threadIdx.x;
    const int lane = t & 63;
    const int r    = t >> 6;                       // wave id, wave-uniform
    const long long row = (long long)blockIdx.x * 4 + r;
    const float* src = x + row * WW;
    char* Lrow = (char*)&lds[r][0];

    // byte-offset XOR swizzle (bits 4..6 ^= bits 7..9) — keeps 16B alignment
    #define SWZ(b) ((b) ^ ((((b) >> 7) & 7) << 4))

    // Phase 1: coalesced row load -> swizzled LDS
    #pragma unroll
    for (int g = 0; g < 4; g++) {
        const int c = g * 256 + lane * 4;          // float index, 16B aligned
        float4 v = *(const float4*)(src + c);
        *(float4*)(Lrow + SWZ(c * 4)) = v;
    }

    const int j0 = lane * 16;                      // outputs j0..j0+15

    // Phase 2a: preload the full 18-float4 window into registers.
    float4 v[18];
    #pragma unroll
    for (int i = 0; i < 18; i++) {
        const int col = j0 - 28 + i * 4;           // multiple of 4
        const bool in = ((unsigned)col < (unsigned)WW);  // fully in (<=1020) or out
        const int cc = in ? col : 0;
        float4 vv = *(const float4*)(Lrow + SWZ(cc * 4));
        if (!in) vv = make_float4(0.f, 0.f, 0.f, 0.f);
        v[i] = vv;
    }

    // Phase 2b: 816 FMAs, input-stationary over the register window.
    float acc[16];
    #pragma unroll
    for (int d = 0; d < 16; d++) acc[d] = 0.f;

    #pragma unroll
    for (int i = 0; i < 18; i++) {
        const float vq[4] = {v[i].x, v[i].y, v[i].z, v[i].w};
        #pragma unroll
        for (int q = 0; q < 4; q++) {
            const int wi = i * 4 + q;              // window index: col j0-28+wi
            #pragma unroll
            for (int d = 0; d < 16; d++) {
                const int k = wi - 3 - d;          // compile-time tap index
                if (k >= 0 && k < KS)
                    acc[d] = fmaf(gw.w[k], vq[q], acc[d]);
            }
        }
    }

    // Phase 3: acc -> LDS (swizzled)
    #pragma unroll
    for (int g = 0; g < 4; g++) {
        const int c = j0 + g * 4;
        *(float4*)(Lrow + SWZ(c * 4)) =
            make_float4(acc[g*4], acc[g*4+1], acc[g*4+2], acc[g*4+3]);
    }

    // Phase 4: coalesced read-back -> coalesced global store
    float* dst = tmp + row * WW;
    #pragma unroll
    for (int g = 0; g < 4; g++) {
        const int c = g * 256 + lane * 4;
        float4 vv = *(const float4*)(Lrow + SWZ(c * 4));
        *(float4*)(dst + c) = vv;
    }
    #undef SWZ
}

// ---------------------------------------------------------------------------
// Vertical 51-tap blur + screen blend + clamp, LDS-staged.
// R4 change: tile 128x64 -> 64x64. LDS 57 KB -> 29 KB, so 2 -> 5 blocks/CU
// (occupancy 18% -> ~60% theoretical): R3's win was capped by the occupancy
// cliff (stage->sync->compute serialization with only 8 waves/CU). Thread =
// 1 col x 16 rows; ds_read_b32 lane-stride-4B (2-way alias = free), each LDS
// read feeds 16 FMAs. Staging redundancy unchanged (1.78x, vertical halo).
// ---------------------------------------------------------------------------
__global__ __launch_bounds__(256) void vblend_kernel(const float* __restrict__ tmp,
                                                     const float* __restrict__ x,
                                                     float* __restrict__ out,
                                                     GaussW gw,
                                                     const float* __restrict__ amountp)
{
    __shared__ __align__(16) float s[114 * 64];    // 29 KB

    const int t      = threadIdx.x;
    const int bid    = blockIdx.x;
    const int plane  = bid >> 8;            // 256 tiles per plane
    const int rem    = bid & 255;
    const int tile_x = rem >> 4;            // 16 col-tiles of 64
    const int tile_y = rem & 15;            // inner -> vertical L2 reuse
    const int cb     = tile_x * 64;         // col base
    const int rb     = tile_y * 64;         // output rows rb..rb+63

    const float* tpl = tmp + (size_t)plane * PLANE;

    // Stage tmp rows rb-25 .. rb+88 (114) x cols cb..cb+63 into LDS.
    // 1824 float4 total; thread t does idx = it*256 + t (coalesced 256B runs).
    #pragma unroll
    for (int it = 0; it < 8; it++) {
        const int idx = it * 256 + t;              // float4 index
        if (idx < 114 * 16) {
            const int row = idx >> 4;              // 0..113
            const int c4  = idx & 15;
            const int gr  = rb - 25 + row;
            const int grc = min(max(gr, 0), HH - 1);
            float4 v = *(const float4*)(tpl + (size_t)grc * WW + cb + c4 * 4);
            if ((unsigned)gr >= (unsigned)HH) v = make_float4(0.f, 0.f, 0.f, 0.f);
            *(float4*)(&s[row * 64 + c4 * 4]) = v;
        }
    }
    __syncthreads();

    const int lane = t & 63;
    const int wid  = t >> 6;                // wave-uniform
    const int lr0  = wid * 16;              // local output row group (0/16/32/48)

    float acc[16];
    #pragma unroll
    for (int j = 0; j < 16; j++) acc[j] = 0.f;

    // LDS rows lr0+i, i in [0,65] -> [0,113]: always in range, zeros baked in.
    #pragma unroll
    for (int i = 0; i < 66; i++) {
        const float v = s[(lr0 + i) * 64 + lane];
        #pragma unroll
        for (int j = 0; j < 16; j++) {
            const int k = i - j;                  // compile-time tap index
            if (k >= 0 && k < KS)
                acc[j] = fmaf(gw.w[k], v, acc[j]);
        }
    }

    const float p = amountp[0];
    const float sc = 1.2f * (0.4f / (1.f + expf(-p)));   // 1.2 * amount

    const int r0 = rb + lr0;
    const int c0 = cb + lane;
    const float* xp = x   + (size_t)plane * PLANE + c0;
    float*       op = out + (size_t)plane * PLANE + c0;
    #pragma unroll
    for (int j = 0; j < 16; j++) {
        const float xv = xp[(size_t)(r0 + j) * WW];
        float res = 1.f - (1.f - xv) * (1.f - sc * acc[j]);
        res = fminf(fmaxf(res, 0.f), 1.f);
        op[(size_t)(r0 + j) * WW] = res;
    }
}

// ---------------------------------------------------------------------------
extern "C" void kernel_launch(void* const* d_in, const int* in_sizes, int n_in,
                              void* d_out, int out_size, void* d_ws, size_t ws_size,
                              hipStream_t stream)
{
    const float* x       = (const float*)d_in[0];
    const float* amountp = (const float*)d_in[1];
    float* out = (float*)d_out;
    float* tmp = (float*)d_ws;

    // Gaussian weights (sigma=15, size 51), normalized — identical every call.
    GaussW gw;
    {
        double e[KS], sum = 0.0;
        for (int i = 0; i < KS; i++) {
            const double d = (double)(i - RAD);
            e[i] = exp(-d * d / (2.0 * 15.0 * 15.0));
            sum += e[i];
        }
        for (int i = 0; i < KS; i++) gw.w[i] = (float)(e[i] / sum);
    }

    const int total_planes = in_sizes[0] / PLANE;      // 24
    const size_t plane_bytes = (size_t)PLANE * sizeof(float);
    int P = (int)(ws_size / plane_bytes);
    if (P < 1) P = 1;
    if (P > total_planes) P = total_planes;

    for (int p0 = 0; p0 < total_planes; p0 += P) {
        const int pc = (total_planes - p0 < P) ? (total_planes - p0) : P;
        hblur_kernel<<<pc * 256, 256, 0, stream>>>(x + (size_t)p0 * PLANE, tmp, gw);
        vblend_kernel<<<pc * 256, 256, 0, stream>>>(tmp,
                                                    x + (size_t)p0 * PLANE,
                                                    out + (size_t)p0 * PLANE,
                                                    gw, amountp);
    }
}